// Round 10
// baseline (95.285 us; speedup 1.0000x reference)
//
#include <hip/hip_runtime.h>
#include <stdint.h>

// Problem constants (from the reference)
constexpr int BATCH       = 32;
constexpr int NUM_WINDOWS = 1020;
constexpr int FLAT        = 128;   // num_vars * window_size * k
constexpr int VOCAB_ROWS  = 2048;  // power of two -> mod is a mask
constexpr int EMBED_DIM   = 512;
constexpr unsigned long long BIG_PRIME = 17461204521323ull;

using ull = unsigned long long;
typedef int   vint4   __attribute__((ext_vector_type(4)));
typedef float vfloat4 __attribute__((ext_vector_type(4)));

// Reference: h=0; for t in flat: h = (h + t + 1) * P   (int64, wrapping)
//   ==> h = sum_{i=0..127} (t_i + 1) * P^(128 - i)   mod 2^64
// (signed wrap == unsigned wrap bitwise; t in [0,32) widens losslessly).
struct Pows { ull v[FLAT + 1]; };
constexpr Pows make_pows() {
    Pows p{};
    p.v[0] = 1ull;
    for (int i = 1; i <= FLAT; ++i) p.v[i] = p.v[i - 1] * BIG_PRIME;
    return p;
}
__constant__ Pows c_pows = make_pows();

// Kernel 1 — hash only. One wave per TOKEN PAIR:
//  lanes 0-31 cover token A's 128 ints (vint4 each), 32-63 token B's;
//  4 mult-adds vs the compile-time power table; 5-step xor-butterfly stays
//  within each 32-lane half (bit 5 never flips); lane 0 of each half writes
//  the masked token id to the workspace. Pure 16.7 MB streaming read.
__global__ __launch_bounds__(256) void hash_kernel(
    const int* __restrict__ fuzz,
    int* __restrict__ tok_ids,
    int n_pairs)
{
    const int gtid = blockIdx.x * blockDim.x + threadIdx.x;
    const int pair = gtid >> 6;
    const int lane = threadIdx.x & 63;
    if (pair >= n_pairs) return;

    const int half = lane >> 5;
    const int j    = lane & 31;

    const vint4 t = *(reinterpret_cast<const vint4*>(fuzz + (size_t)pair * (2 * FLAT)) + lane);

    const int e = 4 * j;
    ull h = (ull)(unsigned)(t.x + 1) * c_pows.v[FLAT - e]
          + (ull)(unsigned)(t.y + 1) * c_pows.v[FLAT - e - 1]
          + (ull)(unsigned)(t.z + 1) * c_pows.v[FLAT - e - 2]
          + (ull)(unsigned)(t.w + 1) * c_pows.v[FLAT - e - 3];

    #pragma unroll
    for (int off = 16; off > 0; off >>= 1)
        h += (ull)__shfl_xor((long long)h, off, 64);

    if (j == 0)
        tok_ids[2 * pair + half] = (int)(h & (ull)(VOCAB_ROWS - 1));
}

// Kernel 2 — gather only. One wave per output row:
//  tiny idx load (one address per wave, cache-broadcast) -> 2 KB row copy as
//  2 x float4 per lane, single contiguous 1 KiB segment per instruction.
//  Short dependency chain + tiny VGPR footprint -> full occupancy, 32K waves
//  of TLP; emb (4 MB) is L2-resident so gathers don't touch HBM after warmup.
__global__ __launch_bounds__(256) void gather_kernel(
    const int* __restrict__ tok_ids,
    const float* __restrict__ emb,
    float* __restrict__ out,
    int n_tokens)
{
    const int gtid = blockIdx.x * blockDim.x + threadIdx.x;
    const int row  = gtid >> 6;
    const int lane = threadIdx.x & 63;
    if (row >= n_tokens) return;

    const int tok = tok_ids[row];

    const vfloat4* src = reinterpret_cast<const vfloat4*>(emb + (size_t)tok * EMBED_DIM);
    vfloat4*       dst = reinterpret_cast<vfloat4*>(out + (size_t)row * EMBED_DIM);
    dst[lane]      = src[lane];
    dst[lane + 64] = src[lane + 64];
}

extern "C" void kernel_launch(void* const* d_in, const int* in_sizes, int n_in,
                              void* d_out, int out_size, void* d_ws, size_t ws_size,
                              hipStream_t stream) {
    const int*   fuzz = (const int*)d_in[0];   // int32 on device (harness narrows int64)
    const float* emb  = (const float*)d_in[1]; // f32 [2048,512]
    float*       out  = (float*)d_out;         // f32 [32,1020,512]
    int*         tok  = (int*)d_ws;            // 32640 ints of scratch (ws is >= 130 KB)

    const int n_tokens = BATCH * NUM_WINDOWS;  // 32640 (even)
    const int n_pairs  = n_tokens / 2;         // 16320 hash waves

    const int threads = 256;                   // 4 waves/block
    const int hash_blocks   = (n_pairs  * 64 + threads - 1) / threads;  // 4080
    const int gather_blocks = (n_tokens * 64 + threads - 1) / threads;  // 8160

    hash_kernel<<<hash_blocks, threads, 0, stream>>>(fuzz, tok, n_pairs);
    gather_kernel<<<gather_blocks, threads, 0, stream>>>(tok, emb, out, n_tokens);
}

// Round 11
// 93.596 us; speedup vs baseline: 1.0181x; 1.0181x over previous
//
#include <hip/hip_runtime.h>
#include <stdint.h>

// Problem constants (from the reference)
constexpr int BATCH       = 32;
constexpr int NUM_WINDOWS = 1020;
constexpr int FLAT        = 128;   // num_vars * window_size * k
constexpr int VOCAB_ROWS  = 2048;  // power of two -> mod is a mask
constexpr int EMBED_DIM   = 512;
constexpr unsigned long long BIG_PRIME = 17461204521323ull;

using ull = unsigned long long;
typedef int   vint2   __attribute__((ext_vector_type(2)));
typedef int   vint4   __attribute__((ext_vector_type(4)));
typedef float vfloat4 __attribute__((ext_vector_type(4)));

// Reference: h=0; for t in flat: h = (h + t + 1) * P   (int64, wrapping)
//   ==> h = sum_{i=0..127} (t_i + 1) * P^(128 - i)   mod 2^64
// (signed wrap == unsigned wrap bitwise; t in [0,32) widens losslessly).
struct Pows { ull v[FLAT + 1]; };
constexpr Pows make_pows() {
    Pows p{};
    p.v[0] = 1ull;
    for (int i = 1; i <= FLAT; ++i) p.v[i] = p.v[i - 1] * BIG_PRIME;
    return p;
}
__constant__ Pows c_pows = make_pows();

// Kernel 1 — hash only (measured ~3 us class: pure 16.7 MB stream).
// One wave per TOKEN PAIR: lanes 0-31 token A, 32-63 token B; vint4/lane;
// 4 mult-adds vs compile-time power table; 5-step xor-butterfly within each
// 32-lane half; one lane per half writes the masked token id.
__global__ __launch_bounds__(256) void hash_kernel(
    const int* __restrict__ fuzz,
    int* __restrict__ tok_ids,
    int n_pairs)
{
    const int gtid = blockIdx.x * blockDim.x + threadIdx.x;
    const int pair = gtid >> 6;
    const int lane = threadIdx.x & 63;
    if (pair >= n_pairs) return;

    const int half = lane >> 5;
    const int j    = lane & 31;

    const vint4 t = *(reinterpret_cast<const vint4*>(fuzz + (size_t)pair * (2 * FLAT)) + lane);

    const int e = 4 * j;
    ull h = (ull)(unsigned)(t.x + 1) * c_pows.v[FLAT - e]
          + (ull)(unsigned)(t.y + 1) * c_pows.v[FLAT - e - 1]
          + (ull)(unsigned)(t.z + 1) * c_pows.v[FLAT - e - 2]
          + (ull)(unsigned)(t.w + 1) * c_pows.v[FLAT - e - 3];

    #pragma unroll
    for (int off = 16; off > 0; off >>= 1)
        h += (ull)__shfl_xor((long long)h, off, 64);

    if (j == 0)
        tok_ids[2 * pair + half] = (int)(h & (ull)(VOCAB_ROWS - 1));
}

// Kernel 2 — gather, restructured for MLP + L2 hygiene:
//  - one wave per TWO rows: idx pair loaded as a single broadcast int2, then
//    ALL FOUR 16B row-segment loads issued before any store (4 outstanding
//    loads/lane vs 2, hides L2/L3 latency)
//  - emb loads stay cacheable (4 MB table should sit in L2/L3)
//  - out stores are NONTEMPORAL: the 67 MB write stream is never re-read;
//    keeping it out of L2 stops it sweeping the embedding table out of the
//    4 MiB/XCD caches (write-allocate thrash theory)
__global__ __launch_bounds__(256) void gather_kernel(
    const int* __restrict__ tok_ids,
    const float* __restrict__ emb,
    float* __restrict__ out,
    int n_pairs)
{
    const int gtid = blockIdx.x * blockDim.x + threadIdx.x;
    const int pair = gtid >> 6;
    const int lane = threadIdx.x & 63;
    if (pair >= n_pairs) return;

    const vint2 tt = *reinterpret_cast<const vint2*>(tok_ids + 2 * pair);

    const vfloat4* s0 = reinterpret_cast<const vfloat4*>(emb + (size_t)tt.x * EMBED_DIM);
    const vfloat4* s1 = reinterpret_cast<const vfloat4*>(emb + (size_t)tt.y * EMBED_DIM);
    vfloat4* d0 = reinterpret_cast<vfloat4*>(out + (size_t)(2 * pair)     * EMBED_DIM);
    vfloat4* d1 = reinterpret_cast<vfloat4*>(out + (size_t)(2 * pair + 1) * EMBED_DIM);

    // 4 independent loads in flight, then 4 stores (compiler keeps this order:
    // stores depend on loads, loads have no deps between them).
    const vfloat4 a = s0[lane];
    const vfloat4 b = s0[lane + 64];
    const vfloat4 c = s1[lane];
    const vfloat4 d = s1[lane + 64];
    __builtin_nontemporal_store(a, d0 + lane);
    __builtin_nontemporal_store(b, d0 + lane + 64);
    __builtin_nontemporal_store(c, d1 + lane);
    __builtin_nontemporal_store(d, d1 + lane + 64);
}

extern "C" void kernel_launch(void* const* d_in, const int* in_sizes, int n_in,
                              void* d_out, int out_size, void* d_ws, size_t ws_size,
                              hipStream_t stream) {
    const int*   fuzz = (const int*)d_in[0];   // int32 on device (harness narrows int64)
    const float* emb  = (const float*)d_in[1]; // f32 [2048,512]
    float*       out  = (float*)d_out;         // f32 [32,1020,512]
    int*         tok  = (int*)d_ws;            // 32640 ints of scratch

    const int n_tokens = BATCH * NUM_WINDOWS;  // 32640 (even)
    const int n_pairs  = n_tokens / 2;         // 16320 waves each kernel

    const int threads = 256;                   // 4 waves/block
    const int blocks  = (n_pairs * 64 + threads - 1) / threads;  // 4080

    hash_kernel<<<blocks, threads, 0, stream>>>(fuzz, tok, n_pairs);
    gather_kernel<<<blocks, threads, 0, stream>>>(tok, emb, out, n_pairs);
}